// Round 2
// baseline (353.859 us; speedup 1.0000x reference)
//
#include <hip/hip_runtime.h>

// Problem constants (from reference):
//   B=1024 batches, S=200 seq, D=64 dim, C=256 clusters
// Outputs (concat in d_out, all read back as float32):
//   out[0] cluster_emb  [B,C,D] = 16,777,216 f32
//   out[1] cluster_mask [B,C,S] = 52,428,800 f32 (0.0/1.0 values)
#define NB 1024
#define NS 200
#define ND 64
#define NC 256

// Native vector type: __builtin_nontemporal_store rejects HIP's float4 class.
typedef float v4f __attribute__((ext_vector_type(4)));

__global__ __launch_bounds__(256) void s3rec_cluster_kernel(
    const float* __restrict__ x,       // [B,S,D]
    const int*   __restrict__ labels,  // [B,S]
    const int*   __restrict__ amask,   // [B,S]
    float* __restrict__ out_emb,       // [B,C,D]
    float* __restrict__ out_mask)      // [B,C,S]
{
    // 64 KB accumulator + ~1.8 KB metadata; gfx950 allows up to 160 KB/WG.
    __shared__ __align__(16) float s_emb[NC * ND];   // 65536 B
    __shared__ int   s_lab[NS];                      // label if masked else -1
    __shared__ float s_inv[NC];

    const int b = blockIdx.x;
    const int t = threadIdx.x;

    // --- stage labels (packed with mask) ---
    for (int i = t; i < NS; i += 256) {
        const int l = labels[b * NS + i];
        const int m = amask [b * NS + i];
        s_lab[i] = (m != 0) ? l : -1;
    }
    // --- zero the accumulator ---
    for (int i = t; i < NC * ND; i += 256) s_emb[i] = 0.0f;
    __syncthreads();

    // --- write cluster_mask [C,S] for this batch: coalesced v4f stores ---
    // 51200 floats = 12800 vec4; row length S=200 is a multiple of 4, so a
    // vec4 never straddles rows. c = i4/50, s0 = (i4%50)*4.
    v4f* om4 = reinterpret_cast<v4f*>(out_mask + (size_t)b * (NC * NS));
    for (int i4 = t; i4 < (NC * NS) / 4; i4 += 256) {
        const int c  = i4 / 50;
        const int s0 = (i4 - c * 50) * 4;
        v4f v;
        v.x = (s_lab[s0 + 0] == c) ? 1.0f : 0.0f;
        v.y = (s_lab[s0 + 1] == c) ? 1.0f : 0.0f;
        v.z = (s_lab[s0 + 2] == c) ? 1.0f : 0.0f;
        v.w = (s_lab[s0 + 3] == c) ? 1.0f : 0.0f;
        __builtin_nontemporal_store(v, &om4[i4]);
    }

    // --- accumulate embeddings into LDS via atomics ---
    // Wave w takes s = w, w+4, ...; lane = d. x loads: 64 consecutive f32 per
    // wave (fully coalesced). LDS atomicAdd: 64 lanes -> 64 consecutive
    // addresses of one row (2 lanes/bank, conflict-free).
    const int lane = t & 63;
    const int w    = t >> 6;
    const float* xb = x + (size_t)b * NS * ND;
    for (int s = w; s < NS; s += 4) {
        const int c = s_lab[s];
        if (c >= 0) {
            atomicAdd(&s_emb[c * ND + lane], xb[s * ND + lane]);
        }
    }

    // --- per-cluster count -> inverse (thread t owns cluster t) ---
    int cnt = 0;
    for (int s = 0; s < NS; ++s) cnt += (s_lab[s] == t) ? 1 : 0;
    s_inv[t] = (cnt > 0) ? (1.0f / (float)cnt) : 0.0f;
    __syncthreads();

    // --- scaled write of cluster_emb [C,D]: vec4, cluster = (i4*4)/64 ---
    v4f* oe4 = reinterpret_cast<v4f*>(out_emb + (size_t)b * (NC * ND));
    const v4f* se4 = reinterpret_cast<const v4f*>(s_emb);
    for (int i4 = t; i4 < (NC * ND) / 4; i4 += 256) {
        const float inv = s_inv[i4 >> 4];
        v4f v = se4[i4];
        v *= inv;
        __builtin_nontemporal_store(v, &oe4[i4]);
    }
}

extern "C" void kernel_launch(void* const* d_in, const int* in_sizes, int n_in,
                              void* d_out, int out_size, void* d_ws, size_t ws_size,
                              hipStream_t stream) {
    const float* x      = (const float*)d_in[0];  // [B,S,D] f32
    const int*   labels = (const int*)  d_in[1];  // [B,S]   i32
    const int*   amask  = (const int*)  d_in[2];  // [B,S]   i32

    float* out_emb  = (float*)d_out;                          // [B,C,D]
    float* out_mask = out_emb + (size_t)NB * NC * ND;         // [B,C,S]

    s3rec_cluster_kernel<<<dim3(NB), dim3(256), 0, stream>>>(
        x, labels, amask, out_emb, out_mask);
}